// Round 3
// baseline (698.657 us; speedup 1.0000x reference)
//
#include <hip/hip_runtime.h>
#include <math.h>

// Problem: x [8,128,256,256] f32, weights [128] f32.
// out[b,i,h,w] = (softmax(weights)*128)[rank(i within column)] * rsqrt(x^2+eps)
// rank[i] = #{j<i: x[j] >= x[i]} + #{j>i: x[j] > x[i]}  (stable descending rank)
//
// R5: VALU-issue-bound (VALUBusy 95-98%; R4 proved spill was off critical path).
// Cut ops/pair 3.75 -> ~3.0: 4x4 microtiles of sign values s = -[vy>vx]
// (v_cmp + v_cndmask, 2 ops) with BOTH accumulations amortized via v_add3
// row-sum/col-sum chains (8+8 adds per 16 pairs). X-octs register-resident
// across the job (one flush); Y streamed in 8-row chunks. Also switches to
// direct float compares: exact tie semantics ([a>=b] = 1-[b>a]) and fixes
// R3/R4's latent int-key subtraction overflow (keys span > 2^31).

#define Q    128
#define TCOL 64
#define HW   65536
#define EPSF 1e-6f

__device__ __forceinline__ unsigned pack4(int a, int b, int c, int d) {
    return (unsigned)a | ((unsigned)b << 8) | ((unsigned)c << 16) | ((unsigned)d << 24);
}

// 4x4 microtile, x rows strictly earlier than y rows.
// s_kj = (vy[j] > vx[k]) ? -1 : 0
// ncx[k] += sum_j s_kj   (later-beats-x count, negated)
// cy[j]  += sum_k s_kj   (combined with +bias elsewhere: earlier-ge count)
__device__ __forceinline__ void mt44(const float* vx, int* ncx,
                                     const float* vy, int* cy) {
    int s[4][4];
    #pragma unroll
    for (int k = 0; k < 4; ++k) {
        #pragma unroll
        for (int j = 0; j < 4; ++j)
            s[k][j] = (vy[j] > vx[k]) ? -1 : 0;
    }
    #pragma unroll
    for (int k = 0; k < 4; ++k)
        ncx[k] += (s[k][0] + s[k][1] + s[k][2]) + s[k][3];   // -> v_add3 chain
    #pragma unroll
    for (int j = 0; j < 4; ++j)
        cy[j]  += (s[0][j] + s[1][j] + s[2][j]) + s[3][j];
}

// Cross job: X rows [X0, X0+NX) all earlier than Y rows [Y0, Y0+NY).
// NX multiple of 8, NY multiple of 8. Bias (1 per earlier partner) applied
// as +8 per oct on the y side; x side flushed negated.
__device__ __forceinline__ void job(const float (*lv)[TCOL], unsigned (*lc)[TCOL],
                                    const int c, const int X0, const int NX,
                                    const int Y0, const int NY) {
    for (int xo = 0; xo < NX; xo += 8) {
        float vx[8]; int ncx[8];
        #pragma unroll
        for (int k = 0; k < 8; ++k) { vx[k] = lv[X0 + xo + k][c]; ncx[k] = 0; }
        for (int yc = 0; yc < NY; yc += 8) {
            float vy[8]; int cy[8];
            #pragma unroll
            for (int j = 0; j < 8; ++j) { vy[j] = lv[Y0 + yc + j][c]; cy[j] = 8; }
            mt44(vx,     ncx,     vy,     cy);
            mt44(vx,     ncx,     vy + 4, cy + 4);
            mt44(vx + 4, ncx + 4, vy,     cy);
            mt44(vx + 4, ncx + 4, vy + 4, cy + 4);
            const int yw = (Y0 + yc) >> 2;
            atomicAdd(&lc[yw][c],     pack4(cy[0], cy[1], cy[2], cy[3]));
            atomicAdd(&lc[yw + 1][c], pack4(cy[4], cy[5], cy[6], cy[7]));
        }
        const int xw = (X0 + xo) >> 2;
        atomicAdd(&lc[xw][c],     pack4(-ncx[0], -ncx[1], -ncx[2], -ncx[3]));
        atomicAdd(&lc[xw + 1][c], pack4(-ncx[4], -ncx[5], -ncx[6], -ncx[7]));
    }
}

// In-register 16-row triangle: 120 pairs, 4 ops each. cd[e] biased by e_local.
__device__ __forceinline__ void tri16(const float (*lv)[TCOL], unsigned (*lc)[TCOL],
                                      const int c, const int B0) {
    float v[16]; int cd[16];
    #pragma unroll
    for (int u = 0; u < 16; ++u) { v[u] = lv[B0 + u][c]; cd[u] = u; }
    #pragma unroll
    for (int a = 0; a < 16; ++a) {
        #pragma unroll
        for (int e = a + 1; e < 16; ++e) {
            const int s = (v[e] > v[a]) ? -1 : 0;
            cd[a] -= s;                 // += [v_e >  v_a]
            cd[e] += s;                 // += [v_a >= v_e] - 1 (bias pre-added)
        }
    }
    #pragma unroll
    for (int n = 0; n < 4; ++n)
        atomicAdd(&lc[(B0 >> 2) + n][c],
                  pack4(cd[4 * n], cd[4 * n + 1], cd[4 * n + 2], cd[4 * n + 3]));
}

__launch_bounds__(256, 4)
__global__ void rank_weight_kernel(const float* __restrict__ x,
                                   const float* __restrict__ weights,
                                   float* __restrict__ out) {
    __shared__ float    lds_v[Q][TCOL];       // 32 KB: raw values
    __shared__ unsigned lds_cnt[Q / 4][TCOL]; // 8 KB: 4 rank-bytes per word

    const int tid = threadIdx.x;
    const int g   = blockIdx.x;
    const int b   = g >> 10;               // 1024 groups of 64 hw per batch
    const int hw0 = (g & 1023) << 6;
    const float* xb = x   + (size_t)b * Q * HW + hw0;
    float*       ob = out + (size_t)b * Q * HW + hw0;

    // ---- stage 128x64 tile: 2048 float4, coalesced ----
    for (int f = tid; f < Q * (TCOL / 4); f += 256) {
        const int r = f >> 4;
        const int p = (f & 15) << 2;
        float4 v = *reinterpret_cast<const float4*>(xb + (size_t)r * HW + p);
        *reinterpret_cast<float4*>(&lds_v[r][p]) = v;
    }
    // ---- zero the packed count accumulators (512 uint4) ----
    {
        uint4 z = {0u, 0u, 0u, 0u};
        for (int i = tid; i < (Q / 4) * TCOL / 4; i += 256)
            reinterpret_cast<uint4*>(&lds_cnt[0][0])[i] = z;
    }

    const int wave = tid >> 6;
    const int c    = tid & 63;

    // ---- softmax(weights)*128 per wave, kept in registers ----
    float w0s, w1s;
    {
        float a0 = weights[c], a1 = weights[c + 64];
        float m = fmaxf(a0, a1);
        #pragma unroll
        for (int off = 32; off; off >>= 1) m = fmaxf(m, __shfl_xor(m, off, 64));
        float e0 = __expf(a0 - m), e1 = __expf(a1 - m);
        float s = e0 + e1;
        #pragma unroll
        for (int off = 32; off; off >>= 1) s += __shfl_xor(s, off, 64);
        const float scale = 128.0f / s;
        w0s = e0 * scale;   // weight for rank c
        w1s = e1 * scale;   // weight for rank c+64
    }
    __syncthreads();

    // ---- per-wave job schedule (same pair partition as R4) ----
    const int B0 = wave << 5;

    // diagonal 32 rows: two 16-row triangles + one 16x16 cross job
    tri16(lds_v, lds_cnt, c, B0);
    tri16(lds_v, lds_cnt, c, B0 + 16);
    job(lds_v, lds_cnt, c, B0, 16, B0 + 16, 16);

    // full cross jobs (32x32): w0:(0,1) w1:(1,2) w2:(2,3) w3:(0,3)
    const int cXb = (wave == 3) ? 0  : (wave << 5);
    const int cYb = (wave == 3) ? 96 : ((wave << 5) + 32);
    job(lds_v, lds_cnt, c, cXb, 32, cYb, 32);

    // half cross jobs (16x32): (0,2) split w0/w1 by X halves; (1,3) w2/w3
    const int hXb = wave << 4;                 // 0,16,32,48
    const int hYb = (wave < 2) ? 64 : 96;
    job(lds_v, lds_cnt, c, hXb, 16, hYb, 32);

    __syncthreads();

    // ---- epilogue: extract ranks, gather weight via shfl, coalesced store ----
    const int R0 = wave << 5;
    #pragma unroll
    for (int mw = 0; mw < 8; ++mw) {
        const unsigned wv = lds_cnt[(R0 >> 2) + mw][c];
        #pragma unroll
        for (int q = 0; q < 4; ++q) {
            const int   r    = R0 + (mw << 2) + q;
            const int   rank = (wv >> (q << 3)) & 0xFF;
            const float xv   = lds_v[r][c];
            const int   rl   = rank & 63;
            const float wa   = __shfl(w0s, rl, 64);
            const float wb   = __shfl(w1s, rl, 64);
            const float wt   = (rank & 64) ? wb : wa;
            ob[(size_t)r * HW + c] = wt * rsqrtf(xv * xv + EPSF);
        }
    }
}

extern "C" void kernel_launch(void* const* d_in, const int* in_sizes, int n_in,
                              void* d_out, int out_size, void* d_ws, size_t ws_size,
                              hipStream_t stream) {
    const float* x  = (const float*)d_in[0];
    const float* wt = (const float*)d_in[1];
    float* out      = (float*)d_out;

    dim3 grid(8192), block(256);   // 524288 columns / 64 per block
    hipLaunchKernelGGL(rank_weight_kernel, grid, block, 0, stream, x, wt, out);
}

// Round 4
// 648.593 us; speedup vs baseline: 1.0772x; 1.0772x over previous
//
#include <hip/hip_runtime.h>
#include <math.h>

// Problem: x [8,128,256,256] f32, weights [128] f32.
// out[b,i,h,w] = (softmax(weights)*128)[rank(i within column)] * rsqrt(x^2+eps)
// rank[i] = #{j<i: x[j] >= x[i]} + #{j>i: x[j] > x[i]}  (stable descending rank)
//
// R6: R5 proved op-count alone isn't the metric: v_cmp+v_cndmask sign
// production carries a hazard tax (VALU->SGPR->VALU lane-mask read), making
// 3.0 "ops"/pair slower than R4's 3.5 plain ops. Fix: produce the sign with
// plain full-rate VALU only:  s = __float_as_int(vx - vy) >> 31  (-1 iff
// vy > vx; exact tie -> +0 -> 0, matching [a>=b] = 1-[b>a] semantics).
// 16 sub + 16 ashr + 16 add3 per 4x4 microtile = 3.0 plain slots/pair.
// Everything else identical to R5 (passing): 4x4 microtiles, add3 row/col
// amortization, u8-packed LDS rank merge, shfl weight gather.

#define Q    128
#define TCOL 64
#define HW   65536
#define EPSF 1e-6f

__device__ __forceinline__ unsigned pack4(int a, int b, int c, int d) {
    return (unsigned)a | ((unsigned)b << 8) | ((unsigned)c << 16) | ((unsigned)d << 24);
}

// sign: -1 iff b > a, 0 otherwise (ties -> +0 -> 0). Plain VALU: v_sub_f32 + v_ashrrev_i32.
__device__ __forceinline__ int sgn(float a, float b) {
    return __float_as_int(a - b) >> 31;
}

// 4x4 microtile, x rows strictly earlier than y rows.
// s_kj = -[vy_j > vx_k]
// ncx[k] += sum_j s_kj   (later-beats-x count, negated)
// cy[j]  += sum_k s_kj   (with +bias at init: earlier-ge count)
__device__ __forceinline__ void mt44(const float* vx, int* ncx,
                                     const float* vy, int* cy) {
    int s[4][4];
    #pragma unroll
    for (int k = 0; k < 4; ++k) {
        #pragma unroll
        for (int j = 0; j < 4; ++j)
            s[k][j] = sgn(vx[k], vy[j]);
    }
    #pragma unroll
    for (int k = 0; k < 4; ++k)
        ncx[k] += (s[k][0] + s[k][1] + s[k][2]) + s[k][3];   // -> v_add3 chain
    #pragma unroll
    for (int j = 0; j < 4; ++j)
        cy[j]  += (s[0][j] + s[1][j] + s[2][j]) + s[3][j];
}

// Cross job: X rows [X0, X0+NX) all earlier than Y rows [Y0, Y0+NY).
// NX, NY multiples of 8. Bias (1 per earlier partner) applied as +8 per oct
// on the y side; x side flushed negated.
__device__ __forceinline__ void job(const float (*lv)[TCOL], unsigned (*lc)[TCOL],
                                    const int c, const int X0, const int NX,
                                    const int Y0, const int NY) {
    for (int xo = 0; xo < NX; xo += 8) {
        float vx[8]; int ncx[8];
        #pragma unroll
        for (int k = 0; k < 8; ++k) { vx[k] = lv[X0 + xo + k][c]; ncx[k] = 0; }
        for (int yc = 0; yc < NY; yc += 8) {
            float vy[8]; int cy[8];
            #pragma unroll
            for (int j = 0; j < 8; ++j) { vy[j] = lv[Y0 + yc + j][c]; cy[j] = 8; }
            mt44(vx,     ncx,     vy,     cy);
            mt44(vx,     ncx,     vy + 4, cy + 4);
            mt44(vx + 4, ncx + 4, vy,     cy);
            mt44(vx + 4, ncx + 4, vy + 4, cy + 4);
            const int yw = (Y0 + yc) >> 2;
            atomicAdd(&lc[yw][c],     pack4(cy[0], cy[1], cy[2], cy[3]));
            atomicAdd(&lc[yw + 1][c], pack4(cy[4], cy[5], cy[6], cy[7]));
        }
        const int xw = (X0 + xo) >> 2;
        atomicAdd(&lc[xw][c],     pack4(-ncx[0], -ncx[1], -ncx[2], -ncx[3]));
        atomicAdd(&lc[xw + 1][c], pack4(-ncx[4], -ncx[5], -ncx[6], -ncx[7]));
    }
}

// In-register 16-row triangle: 120 pairs. cd[e] biased by e_local.
__device__ __forceinline__ void tri16(const float (*lv)[TCOL], unsigned (*lc)[TCOL],
                                      const int c, const int B0) {
    float v[16]; int cd[16];
    #pragma unroll
    for (int u = 0; u < 16; ++u) { v[u] = lv[B0 + u][c]; cd[u] = u; }
    #pragma unroll
    for (int a = 0; a < 16; ++a) {
        #pragma unroll
        for (int e = a + 1; e < 16; ++e) {
            const int s = sgn(v[a], v[e]);  // -1 iff v[e] > v[a]
            cd[a] -= s;                 // += [v_e >  v_a]
            cd[e] += s;                 // += [v_a >= v_e] - 1 (bias pre-added)
        }
    }
    #pragma unroll
    for (int n = 0; n < 4; ++n)
        atomicAdd(&lc[(B0 >> 2) + n][c],
                  pack4(cd[4 * n], cd[4 * n + 1], cd[4 * n + 2], cd[4 * n + 3]));
}

__launch_bounds__(256, 4)
__global__ void rank_weight_kernel(const float* __restrict__ x,
                                   const float* __restrict__ weights,
                                   float* __restrict__ out) {
    __shared__ float    lds_v[Q][TCOL];       // 32 KB: raw values
    __shared__ unsigned lds_cnt[Q / 4][TCOL]; // 8 KB: 4 rank-bytes per word

    const int tid = threadIdx.x;
    const int g   = blockIdx.x;
    const int b   = g >> 10;               // 1024 groups of 64 hw per batch
    const int hw0 = (g & 1023) << 6;
    const float* xb = x   + (size_t)b * Q * HW + hw0;
    float*       ob = out + (size_t)b * Q * HW + hw0;

    // ---- stage 128x64 tile: 2048 float4, coalesced ----
    for (int f = tid; f < Q * (TCOL / 4); f += 256) {
        const int r = f >> 4;
        const int p = (f & 15) << 2;
        float4 v = *reinterpret_cast<const float4*>(xb + (size_t)r * HW + p);
        *reinterpret_cast<float4*>(&lds_v[r][p]) = v;
    }
    // ---- zero the packed count accumulators (512 uint4) ----
    {
        uint4 z = {0u, 0u, 0u, 0u};
        for (int i = tid; i < (Q / 4) * TCOL / 4; i += 256)
            reinterpret_cast<uint4*>(&lds_cnt[0][0])[i] = z;
    }

    const int wave = tid >> 6;
    const int c    = tid & 63;

    // ---- softmax(weights)*128 per wave, kept in registers ----
    float w0s, w1s;
    {
        float a0 = weights[c], a1 = weights[c + 64];
        float m = fmaxf(a0, a1);
        #pragma unroll
        for (int off = 32; off; off >>= 1) m = fmaxf(m, __shfl_xor(m, off, 64));
        float e0 = __expf(a0 - m), e1 = __expf(a1 - m);
        float s = e0 + e1;
        #pragma unroll
        for (int off = 32; off; off >>= 1) s += __shfl_xor(s, off, 64);
        const float scale = 128.0f / s;
        w0s = e0 * scale;   // weight for rank c
        w1s = e1 * scale;   // weight for rank c+64
    }
    __syncthreads();

    // ---- per-wave job schedule (same pair partition as R4/R5) ----
    const int B0 = wave << 5;

    // diagonal 32 rows: two 16-row triangles + one 16x16 cross job
    tri16(lds_v, lds_cnt, c, B0);
    tri16(lds_v, lds_cnt, c, B0 + 16);
    job(lds_v, lds_cnt, c, B0, 16, B0 + 16, 16);

    // full cross jobs (32x32): w0:(0,1) w1:(1,2) w2:(2,3) w3:(0,3)
    const int cXb = (wave == 3) ? 0  : (wave << 5);
    const int cYb = (wave == 3) ? 96 : ((wave << 5) + 32);
    job(lds_v, lds_cnt, c, cXb, 32, cYb, 32);

    // half cross jobs (16x32): (0,2) split w0/w1 by X halves; (1,3) w2/w3
    const int hXb = wave << 4;                 // 0,16,32,48
    const int hYb = (wave < 2) ? 64 : 96;
    job(lds_v, lds_cnt, c, hXb, 16, hYb, 32);

    __syncthreads();

    // ---- epilogue: extract ranks, gather weight via shfl, coalesced store ----
    const int R0 = wave << 5;
    #pragma unroll
    for (int mw = 0; mw < 8; ++mw) {
        const unsigned wv = lds_cnt[(R0 >> 2) + mw][c];
        #pragma unroll
        for (int q = 0; q < 4; ++q) {
            const int   r    = R0 + (mw << 2) + q;
            const int   rank = (wv >> (q << 3)) & 0xFF;
            const float xv   = lds_v[r][c];
            const int   rl   = rank & 63;
            const float wa   = __shfl(w0s, rl, 64);
            const float wb   = __shfl(w1s, rl, 64);
            const float wt   = (rank & 64) ? wb : wa;
            ob[(size_t)r * HW + c] = wt * rsqrtf(xv * xv + EPSF);
        }
    }
}

extern "C" void kernel_launch(void* const* d_in, const int* in_sizes, int n_in,
                              void* d_out, int out_size, void* d_ws, size_t ws_size,
                              hipStream_t stream) {
    const float* x  = (const float*)d_in[0];
    const float* wt = (const float*)d_in[1];
    float* out      = (float*)d_out;

    dim3 grid(8192), block(256);   // 524288 columns / 64 per block
    hipLaunchKernelGGL(rank_weight_kernel, grid, block, 0, stream, x, wt, out);
}